// Round 1
// baseline (850.503 us; speedup 1.0000x reference)
//
#include <hip/hip_runtime.h>

#define N_NODES   100000
#define N_EDGES   3200000
#define N_FEAT    128
#define HIDDEN    16
#define N_CLASSES 10
#define N_GRAPHS  512

// ---------------- CSR build ----------------

__global__ void count_kernel(const int* __restrict__ dst, int* __restrict__ cnt) {
    int e = blockIdx.x * 256 + threadIdx.x;
    if (e < N_EDGES) atomicAdd(&cnt[dst[e]], 1);
}

// block scans 1024 counts (256 thr x 4); also emits dinv = rsqrt(deg+1)
__global__ void scan1_kernel(const int* __restrict__ cnt, int* __restrict__ row_ptr,
                             float* __restrict__ dinv, int* __restrict__ blkSums) {
    __shared__ int sdata[256];
    int tid  = threadIdx.x;
    int base = blockIdx.x * 1024 + tid * 4;
    int vals[4];
    int tsum = 0;
#pragma unroll
    for (int i = 0; i < 4; ++i) {
        int idx = base + i;
        int v = (idx < N_NODES) ? cnt[idx] : 0;
        if (idx < N_NODES) dinv[idx] = rsqrtf((float)(v + 1));  // +1 self-loop
        vals[i] = tsum;
        tsum += v;
    }
    sdata[tid] = tsum;
    __syncthreads();
    for (int off = 1; off < 256; off <<= 1) {
        int t = (tid >= off) ? sdata[tid - off] : 0;
        __syncthreads();
        sdata[tid] += t;
        __syncthreads();
    }
    int incl  = sdata[tid];
    int texcl = incl - tsum;
    if (tid == 255) blkSums[blockIdx.x] = incl;
#pragma unroll
    for (int i = 0; i < 4; ++i) {
        int idx = base + i;
        if (idx < N_NODES) row_ptr[idx] = texcl + vals[i];
    }
}

__global__ void scan2_kernel(int* __restrict__ blkSums, int* __restrict__ row_ptr, int nb) {
    __shared__ int sdata[128];
    int tid = threadIdx.x;
    int v = (tid < nb) ? blkSums[tid] : 0;
    sdata[tid] = v;
    __syncthreads();
    for (int off = 1; off < 128; off <<= 1) {
        int t = (tid >= off) ? sdata[tid - off] : 0;
        __syncthreads();
        sdata[tid] += t;
        __syncthreads();
    }
    if (tid < nb) blkSums[tid] = sdata[tid] - v;      // exclusive
    if (tid == 127) row_ptr[N_NODES] = sdata[127];    // total = E
}

__global__ void scan3_kernel(int* __restrict__ row_ptr, const int* __restrict__ blkSums,
                             int* __restrict__ fillcur) {
    int idx = blockIdx.x * 256 + threadIdx.x;
    if (idx < N_NODES) {
        int r = row_ptr[idx] + blkSums[idx >> 10];
        row_ptr[idx] = r;
        fillcur[idx] = r;
    }
}

__global__ void fill_kernel(const int* __restrict__ src, const int* __restrict__ dst,
                            int* __restrict__ fillcur, int* __restrict__ csr) {
    int e = blockIdx.x * 256 + threadIdx.x;
    if (e < N_EDGES) {
        int d = dst[e];
        int slot = atomicAdd(&fillcur[d], 1);
        csr[slot] = src[e];
    }
}

// ---------------- layer kernels ----------------

// g[v] = dinv[v] * (x[v] @ W1), x: [N,128], W: [128,16]
__global__ void transform_x_kernel(const float* __restrict__ x, const float* __restrict__ W,
                                   const float* __restrict__ dinv, float* __restrict__ g) {
    __shared__ float Wl[N_FEAT * HIDDEN];
    int tid = threadIdx.x;
    for (int i = tid; i < N_FEAT * HIDDEN; i += 256) Wl[i] = W[i];
    __syncthreads();
    int v = blockIdx.x * 256 + tid;
    if (v >= N_NODES) return;
    float acc[HIDDEN];
#pragma unroll
    for (int f = 0; f < HIDDEN; ++f) acc[f] = 0.f;
    const float4* xr = (const float4*)(x + (size_t)v * N_FEAT);
#pragma unroll 4
    for (int k4 = 0; k4 < N_FEAT / 4; ++k4) {
        float4 xv = xr[k4];
        const float* wr = &Wl[k4 * 4 * HIDDEN];
#pragma unroll
        for (int f = 0; f < HIDDEN; ++f)
            acc[f] += xv.x * wr[f] + xv.y * wr[HIDDEN + f] +
                      xv.z * wr[2 * HIDDEN + f] + xv.w * wr[3 * HIDDEN + f];
    }
    float di = dinv[v];
    float4* go = (float4*)(g + (size_t)v * HIDDEN);
#pragma unroll
    for (int q = 0; q < 4; ++q) {
        float4 o;
        o.x = di * acc[q * 4 + 0];
        o.y = di * acc[q * 4 + 1];
        o.z = di * acc[q * 4 + 2];
        o.w = di * acc[q * 4 + 3];
        go[q] = o;
    }
}

// g[v] = dinv[v] * (h[v] @ W), h: [N,16], W: [16,16]
__global__ void transform_h_kernel(const float* __restrict__ h, const float* __restrict__ W,
                                   const float* __restrict__ dinv, float* __restrict__ g) {
    __shared__ float Wl[HIDDEN * HIDDEN];
    int tid = threadIdx.x;
    if (tid < HIDDEN * HIDDEN) Wl[tid] = W[tid];
    __syncthreads();
    int v = blockIdx.x * 256 + tid;
    if (v >= N_NODES) return;
    float hv[HIDDEN];
    const float4* hr = (const float4*)(h + (size_t)v * HIDDEN);
#pragma unroll
    for (int q = 0; q < 4; ++q) {
        float4 a = hr[q];
        hv[q * 4 + 0] = a.x; hv[q * 4 + 1] = a.y;
        hv[q * 4 + 2] = a.z; hv[q * 4 + 3] = a.w;
    }
    float acc[HIDDEN];
#pragma unroll
    for (int f = 0; f < HIDDEN; ++f) acc[f] = 0.f;
#pragma unroll
    for (int k = 0; k < HIDDEN; ++k) {
        float hk = hv[k];
#pragma unroll
        for (int f = 0; f < HIDDEN; ++f) acc[f] += hk * Wl[k * HIDDEN + f];
    }
    float di = dinv[v];
    float4* go = (float4*)(g + (size_t)v * HIDDEN);
#pragma unroll
    for (int q = 0; q < 4; ++q) {
        float4 o;
        o.x = di * acc[q * 4 + 0];
        o.y = di * acc[q * 4 + 1];
        o.z = di * acc[q * 4 + 2];
        o.w = di * acc[q * 4 + 3];
        go[q] = o;
    }
}

// h[v][f] = act( dinv[v] * (g[v][f] + sum_{in-edges} g[src][f]) + bias[f] )
// 16 lanes per node, lane = feature
__global__ void aggregate_kernel(const float* __restrict__ g, const int* __restrict__ row_ptr,
                                 const int* __restrict__ csr, const float* __restrict__ dinv,
                                 const float* __restrict__ bias, float* __restrict__ h,
                                 int do_relu) {
    int tid = threadIdx.x;
    int f = tid & 15;
    int v = blockIdx.x * 16 + (tid >> 4);
    if (v >= N_NODES) return;
    int beg = row_ptr[v];
    int end = row_ptr[v + 1];
    float a = g[v * HIDDEN + f];  // self-loop contribution
    for (int j = beg; j < end; ++j) {
        int s = csr[j];
        a += g[s * HIDDEN + f];
    }
    float val = dinv[v] * a + bias[f];
    if (do_relu) val = fmaxf(val, 0.f);
    h[v * HIDDEN + f] = val;
}

// ---------------- pooling + head ----------------

__global__ void pool_kernel(const float* __restrict__ h, const int* __restrict__ batch,
                            float* __restrict__ pooled) {
    int idx = blockIdx.x * 256 + threadIdx.x;
    if (idx < N_NODES * HIDDEN) {
        int v = idx >> 4;
        int f = idx & 15;
        atomicAdd(&pooled[batch[v] * HIDDEN + f], h[idx]);
    }
}

__global__ void head_kernel(const float* __restrict__ pooled, const float* __restrict__ Wlin,
                            const float* __restrict__ blin, float* __restrict__ out) {
    int idx = blockIdx.x * 256 + threadIdx.x;
    if (idx < N_GRAPHS * N_CLASSES) {
        int gi = idx / N_CLASSES;
        int c  = idx % N_CLASSES;
        float s = blin[c];
#pragma unroll
        for (int f = 0; f < HIDDEN; ++f) s += pooled[gi * HIDDEN + f] * Wlin[f * N_CLASSES + c];
        out[idx] = s;
    }
}

// ---------------- launch ----------------

extern "C" void kernel_launch(void* const* d_in, const int* in_sizes, int n_in,
                              void* d_out, int out_size, void* d_ws, size_t ws_size,
                              hipStream_t stream) {
    const float* x     = (const float*)d_in[0];
    const int*   ei    = (const int*)d_in[1];
    const int*   src   = ei;
    const int*   dst   = ei + N_EDGES;
    const int*   batch = (const int*)d_in[2];
    const float* W1 = (const float*)d_in[3];
    const float* b1 = (const float*)d_in[4];
    const float* W2 = (const float*)d_in[5];
    const float* b2 = (const float*)d_in[6];
    const float* W3 = (const float*)d_in[7];
    const float* b3 = (const float*)d_in[8];
    const float* Wlin = (const float*)d_in[9];
    const float* blin = (const float*)d_in[10];
    float* out = (float*)d_out;

    char* w = (char*)d_ws;
    auto alloc = [&](size_t bytes) -> char* {
        char* p = w;
        w += (bytes + 255) & ~(size_t)255;
        return p;
    };
    int*   cnt     = (int*)alloc((size_t)N_NODES * 4);
    int*   row_ptr = (int*)alloc(((size_t)N_NODES + 1) * 4);
    int*   fillcur = (int*)alloc((size_t)N_NODES * 4);
    float* dinv    = (float*)alloc((size_t)N_NODES * 4);
    int*   blkSums = (int*)alloc(512);
    int*   csr     = (int*)alloc((size_t)N_EDGES * 4);
    float* g       = (float*)alloc((size_t)N_NODES * HIDDEN * 4);
    float* hA      = (float*)alloc((size_t)N_NODES * HIDDEN * 4);
    float* hB      = (float*)alloc((size_t)N_NODES * HIDDEN * 4);
    float* pooled  = (float*)alloc((size_t)N_GRAPHS * HIDDEN * 4);

    hipMemsetAsync(cnt, 0, (size_t)N_NODES * 4, stream);
    hipMemsetAsync(pooled, 0, (size_t)N_GRAPHS * HIDDEN * 4, stream);

    int eb  = (N_EDGES + 255) / 256;
    int nb1 = (N_NODES + 1023) / 1024;   // 98 scan blocks
    int nbn = (N_NODES + 255) / 256;
    int ab  = (N_NODES + 15) / 16;

    count_kernel<<<eb, 256, 0, stream>>>(dst, cnt);
    scan1_kernel<<<nb1, 256, 0, stream>>>(cnt, row_ptr, dinv, blkSums);
    scan2_kernel<<<1, 128, 0, stream>>>(blkSums, row_ptr, nb1);
    scan3_kernel<<<nbn, 256, 0, stream>>>(row_ptr, blkSums, fillcur);
    fill_kernel<<<eb, 256, 0, stream>>>(src, dst, fillcur, csr);

    // layer 1
    transform_x_kernel<<<nbn, 256, 0, stream>>>(x, W1, dinv, g);
    aggregate_kernel<<<ab, 256, 0, stream>>>(g, row_ptr, csr, dinv, b1, hA, 1);
    // layer 2
    transform_h_kernel<<<nbn, 256, 0, stream>>>(hA, W2, dinv, g);
    aggregate_kernel<<<ab, 256, 0, stream>>>(g, row_ptr, csr, dinv, b2, hB, 1);
    // layer 3 (no relu)
    transform_h_kernel<<<nbn, 256, 0, stream>>>(hB, W3, dinv, g);
    aggregate_kernel<<<ab, 256, 0, stream>>>(g, row_ptr, csr, dinv, b3, hA, 0);

    pool_kernel<<<(N_NODES * HIDDEN + 255) / 256, 256, 0, stream>>>(hA, batch, pooled);
    head_kernel<<<(N_GRAPHS * N_CLASSES + 255) / 256, 256, 0, stream>>>(pooled, Wlin, blin, out);
}

// Round 2
// 561.072 us; speedup vs baseline: 1.5159x; 1.5159x over previous
//
#include <hip/hip_runtime.h>

#define N_NODES   100000
#define N_EDGES   3200000
#define N_FEAT    128
#define HIDDEN    16
#define N_CLASSES 10
#define N_GRAPHS  512
#define NBUCKET   391      // ceil(N_NODES / 256)
#define EPT       16       // edges per thread in partition (4096/block)

// ---------------- CSR build (two-level counting sort by dst) ----------------

__global__ void bucket_count_kernel(const int* __restrict__ dst, int* __restrict__ bucketCnt) {
    __shared__ int hist[NBUCKET];
    for (int i = threadIdx.x; i < NBUCKET; i += 256) hist[i] = 0;
    __syncthreads();
    int stride = gridDim.x * 256;
    for (int e = blockIdx.x * 256 + threadIdx.x; e < N_EDGES; e += stride)
        atomicAdd(&hist[dst[e] >> 8], 1);
    __syncthreads();
    for (int i = threadIdx.x; i < NBUCKET; i += 256) {
        int c = hist[i];
        if (c) atomicAdd(&bucketCnt[i], c);
    }
}

__global__ void bucket_scan_kernel(const int* __restrict__ bucketCnt, int* __restrict__ bucketBase,
                                   int* __restrict__ bucketCur, int* __restrict__ row_ptr) {
    __shared__ int s[512];
    int tid = threadIdx.x;
    int v = (tid < NBUCKET) ? bucketCnt[tid] : 0;
    s[tid] = v;
    __syncthreads();
    for (int off = 1; off < 512; off <<= 1) {
        int t = (tid >= off) ? s[tid - off] : 0;
        __syncthreads();
        s[tid] += t;
        __syncthreads();
    }
    if (tid < NBUCKET) {
        int base = s[tid] - v;  // exclusive
        bucketBase[tid] = base;
        bucketCur[tid]  = base;
    }
    if (tid == NBUCKET) {                 // total == N_EDGES
        bucketBase[NBUCKET] = s[tid];
        row_ptr[N_NODES]    = s[tid];
    }
}

// scatter packed (src | (dst&255)<<17) into bucket-partitioned array
__global__ void partition_kernel(const int* __restrict__ src, const int* __restrict__ dst,
                                 int* __restrict__ bucketCur, unsigned* __restrict__ part) {
    __shared__ int cnt[NBUCKET];
    __shared__ int base[NBUCKET];
    for (int i = threadIdx.x; i < NBUCKET; i += 256) cnt[i] = 0;
    __syncthreads();
    int blockStart = blockIdx.x * (256 * EPT);
    unsigned rec[EPT];
    int lr[EPT];
    int bkey[EPT];
#pragma unroll
    for (int i = 0; i < EPT; ++i) {
        int e = blockStart + i * 256 + threadIdx.x;
        if (e < N_EDGES) {
            int d = dst[e];
            int b = d >> 8;
            bkey[i] = b;
            lr[i]   = atomicAdd(&cnt[b], 1);
            rec[i]  = (unsigned)src[e] | ((unsigned)(d & 255) << 17);
        } else {
            lr[i] = -1;
        }
    }
    __syncthreads();
    for (int i = threadIdx.x; i < NBUCKET; i += 256) {
        int c = cnt[i];
        base[i] = c ? atomicAdd(&bucketCur[i], c) : 0;
    }
    __syncthreads();
#pragma unroll
    for (int i = 0; i < EPT; ++i)
        if (lr[i] >= 0) part[base[bkey[i]] + lr[i]] = rec[i];
}

// one block per bucket: local count/scan/fill, all LDS; also emits dinv
__global__ void build_csr_kernel(const unsigned* __restrict__ part, const int* __restrict__ bucketBase,
                                 int* __restrict__ row_ptr, float* __restrict__ dinv,
                                 int* __restrict__ csr) {
    __shared__ int ncnt[256];
    __shared__ int s[256];
    int b   = blockIdx.x;
    int tid = threadIdx.x;
    int beg = bucketBase[b], end = bucketBase[b + 1];
    ncnt[tid] = 0;
    __syncthreads();
    for (int j = beg + tid; j < end; j += 256)
        atomicAdd(&ncnt[part[j] >> 17], 1);
    __syncthreads();
    int deg = ncnt[tid];
    s[tid] = deg;
    __syncthreads();
    for (int off = 1; off < 256; off <<= 1) {
        int t = (tid >= off) ? s[tid - off] : 0;
        __syncthreads();
        s[tid] += t;
        __syncthreads();
    }
    int excl = s[tid] - deg;
    int node = b * 256 + tid;
    if (node < N_NODES) {
        row_ptr[node] = beg + excl;
        dinv[node]    = rsqrtf((float)(deg + 1));  // +1 self-loop
    }
    ncnt[tid] = excl;   // reuse as fill cursor (all prior reads of ncnt are done)
    __syncthreads();
    for (int j = beg + tid; j < end; j += 256) {
        unsigned r = part[j];
        int v = r >> 17;
        int slot = beg + atomicAdd(&ncnt[v], 1);
        csr[slot] = (int)(r & 0x1FFFFu);
    }
}

// ---------------- layer kernels ----------------

// g[v] = dinv[v] * (x[v] @ W1), x: [N,128], W: [128,16]
__global__ void transform_x_kernel(const float* __restrict__ x, const float* __restrict__ W,
                                   const float* __restrict__ dinv, float* __restrict__ g) {
    __shared__ float Wl[N_FEAT * HIDDEN];
    int tid = threadIdx.x;
    for (int i = tid; i < N_FEAT * HIDDEN; i += 256) Wl[i] = W[i];
    __syncthreads();
    int v = blockIdx.x * 256 + tid;
    if (v >= N_NODES) return;
    float acc[HIDDEN];
#pragma unroll
    for (int f = 0; f < HIDDEN; ++f) acc[f] = 0.f;
    const float4* xr = (const float4*)(x + (size_t)v * N_FEAT);
#pragma unroll 4
    for (int k4 = 0; k4 < N_FEAT / 4; ++k4) {
        float4 xv = xr[k4];
        const float* wr = &Wl[k4 * 4 * HIDDEN];
#pragma unroll
        for (int f = 0; f < HIDDEN; ++f)
            acc[f] += xv.x * wr[f] + xv.y * wr[HIDDEN + f] +
                      xv.z * wr[2 * HIDDEN + f] + xv.w * wr[3 * HIDDEN + f];
    }
    float di = dinv[v];
    float4* go = (float4*)(g + (size_t)v * HIDDEN);
#pragma unroll
    for (int q = 0; q < 4; ++q) {
        float4 o;
        o.x = di * acc[q * 4 + 0];
        o.y = di * acc[q * 4 + 1];
        o.z = di * acc[q * 4 + 2];
        o.w = di * acc[q * 4 + 3];
        go[q] = o;
    }
}

// g[v] = dinv[v] * (h[v] @ W), h: [N,16], W: [16,16]
__global__ void transform_h_kernel(const float* __restrict__ h, const float* __restrict__ W,
                                   const float* __restrict__ dinv, float* __restrict__ g) {
    __shared__ float Wl[HIDDEN * HIDDEN];
    int tid = threadIdx.x;
    if (tid < HIDDEN * HIDDEN) Wl[tid] = W[tid];
    __syncthreads();
    int v = blockIdx.x * 256 + tid;
    if (v >= N_NODES) return;
    float hv[HIDDEN];
    const float4* hr = (const float4*)(h + (size_t)v * HIDDEN);
#pragma unroll
    for (int q = 0; q < 4; ++q) {
        float4 a = hr[q];
        hv[q * 4 + 0] = a.x; hv[q * 4 + 1] = a.y;
        hv[q * 4 + 2] = a.z; hv[q * 4 + 3] = a.w;
    }
    float acc[HIDDEN];
#pragma unroll
    for (int f = 0; f < HIDDEN; ++f) acc[f] = 0.f;
#pragma unroll
    for (int k = 0; k < HIDDEN; ++k) {
        float hk = hv[k];
#pragma unroll
        for (int f = 0; f < HIDDEN; ++f) acc[f] += hk * Wl[k * HIDDEN + f];
    }
    float di = dinv[v];
    float4* go = (float4*)(g + (size_t)v * HIDDEN);
#pragma unroll
    for (int q = 0; q < 4; ++q) {
        float4 o;
        o.x = di * acc[q * 4 + 0];
        o.y = di * acc[q * 4 + 1];
        o.z = di * acc[q * 4 + 2];
        o.w = di * acc[q * 4 + 3];
        go[q] = o;
    }
}

// h[v][f] = act( dinv[v] * (g[v][f] + sum_{in-edges} g[src][f]) + bias[f] )
__global__ void aggregate_kernel(const float* __restrict__ g, const int* __restrict__ row_ptr,
                                 const int* __restrict__ csr, const float* __restrict__ dinv,
                                 const float* __restrict__ bias, float* __restrict__ h,
                                 int do_relu) {
    int tid = threadIdx.x;
    int f = tid & 15;
    int v = blockIdx.x * 16 + (tid >> 4);
    if (v >= N_NODES) return;
    int beg = row_ptr[v];
    int end = row_ptr[v + 1];
    float a = g[v * HIDDEN + f];  // self-loop contribution
    for (int j = beg; j < end; ++j) {
        int s = csr[j];
        a += g[s * HIDDEN + f];
    }
    float val = dinv[v] * a + bias[f];
    if (do_relu) val = fmaxf(val, 0.f);
    h[v * HIDDEN + f] = val;
}

// ---------------- pooling + head ----------------

__global__ void pool_kernel(const float* __restrict__ h, const int* __restrict__ batch,
                            float* __restrict__ pooled) {
    int idx = blockIdx.x * 256 + threadIdx.x;
    if (idx < N_NODES * HIDDEN) {
        int v = idx >> 4;
        int f = idx & 15;
        atomicAdd(&pooled[batch[v] * HIDDEN + f], h[idx]);
    }
}

__global__ void head_kernel(const float* __restrict__ pooled, const float* __restrict__ Wlin,
                            const float* __restrict__ blin, float* __restrict__ out) {
    int idx = blockIdx.x * 256 + threadIdx.x;
    if (idx < N_GRAPHS * N_CLASSES) {
        int gi = idx / N_CLASSES;
        int c  = idx % N_CLASSES;
        float s = blin[c];
#pragma unroll
        for (int f = 0; f < HIDDEN; ++f) s += pooled[gi * HIDDEN + f] * Wlin[f * N_CLASSES + c];
        out[idx] = s;
    }
}

// ---------------- launch ----------------

extern "C" void kernel_launch(void* const* d_in, const int* in_sizes, int n_in,
                              void* d_out, int out_size, void* d_ws, size_t ws_size,
                              hipStream_t stream) {
    const float* x     = (const float*)d_in[0];
    const int*   ei    = (const int*)d_in[1];
    const int*   src   = ei;
    const int*   dst   = ei + N_EDGES;
    const int*   batch = (const int*)d_in[2];
    const float* W1 = (const float*)d_in[3];
    const float* b1 = (const float*)d_in[4];
    const float* W2 = (const float*)d_in[5];
    const float* b2 = (const float*)d_in[6];
    const float* W3 = (const float*)d_in[7];
    const float* b3 = (const float*)d_in[8];
    const float* Wlin = (const float*)d_in[9];
    const float* blin = (const float*)d_in[10];
    float* out = (float*)d_out;

    char* w = (char*)d_ws;
    auto alloc = [&](size_t bytes) -> char* {
        char* p = w;
        w += (bytes + 255) & ~(size_t)255;
        return p;
    };
    int*   bucketCnt  = (int*)alloc((size_t)NBUCKET * 4);
    int*   bucketBase = (int*)alloc(((size_t)NBUCKET + 1) * 4);
    int*   bucketCur  = (int*)alloc((size_t)NBUCKET * 4);
    int*   row_ptr    = (int*)alloc(((size_t)N_NODES + 1) * 4);
    float* dinv       = (float*)alloc((size_t)N_NODES * 4);
    float* pooled     = (float*)alloc((size_t)N_GRAPHS * HIDDEN * 4);
    int*   csr        = (int*)alloc((size_t)N_EDGES * 4);
    float* g          = (float*)alloc((size_t)N_NODES * HIDDEN * 4);
    // part (12.8 MB) aliases hA+hB: part is dead before hA is first written
    char*  bigbuf     = alloc((size_t)N_EDGES * 4);
    unsigned* part    = (unsigned*)bigbuf;
    float* hA         = (float*)bigbuf;
    float* hB         = hA + (size_t)N_NODES * HIDDEN;

    hipMemsetAsync(bucketCnt, 0, (size_t)NBUCKET * 4, stream);
    hipMemsetAsync(pooled, 0, (size_t)N_GRAPHS * HIDDEN * 4, stream);

    int nbn = (N_NODES + 255) / 256;
    int ab  = (N_NODES + 15) / 16;
    int pb  = (N_EDGES + 256 * EPT - 1) / (256 * EPT);

    bucket_count_kernel<<<512, 256, 0, stream>>>(dst, bucketCnt);
    bucket_scan_kernel<<<1, 512, 0, stream>>>(bucketCnt, bucketBase, bucketCur, row_ptr);
    partition_kernel<<<pb, 256, 0, stream>>>(src, dst, bucketCur, part);
    build_csr_kernel<<<NBUCKET, 256, 0, stream>>>(part, bucketBase, row_ptr, dinv, csr);

    // layer 1
    transform_x_kernel<<<nbn, 256, 0, stream>>>(x, W1, dinv, g);
    aggregate_kernel<<<ab, 256, 0, stream>>>(g, row_ptr, csr, dinv, b1, hA, 1);
    // layer 2
    transform_h_kernel<<<nbn, 256, 0, stream>>>(hA, W2, dinv, g);
    aggregate_kernel<<<ab, 256, 0, stream>>>(g, row_ptr, csr, dinv, b2, hB, 1);
    // layer 3 (no relu)
    transform_h_kernel<<<nbn, 256, 0, stream>>>(hB, W3, dinv, g);
    aggregate_kernel<<<ab, 256, 0, stream>>>(g, row_ptr, csr, dinv, b3, hA, 0);

    pool_kernel<<<(N_NODES * HIDDEN + 255) / 256, 256, 0, stream>>>(hA, batch, pooled);
    head_kernel<<<(N_GRAPHS * N_CLASSES + 255) / 256, 256, 0, stream>>>(pooled, Wlin, blin, out);
}

// Round 3
// 349.325 us; speedup vs baseline: 2.4347x; 1.6062x over previous
//
#include <hip/hip_runtime.h>
#include <hip/hip_fp16.h>

#define N_NODES   100000
#define N_EDGES   3200000
#define N_FEAT    128
#define HIDDEN    16
#define N_CLASSES 10
#define N_GRAPHS  512
#define NBUCKET   391      // ceil(N_NODES / 256)
#define EPT       16       // edges per thread in partition (4096/block)

// ---------------- CSR build (two-level counting sort by dst) ----------------

__global__ void bucket_count_kernel(const int* __restrict__ dst, int* __restrict__ bucketCnt) {
    __shared__ int hist[NBUCKET];
    for (int i = threadIdx.x; i < NBUCKET; i += 256) hist[i] = 0;
    __syncthreads();
    int stride = gridDim.x * 256;
    for (int e = blockIdx.x * 256 + threadIdx.x; e < N_EDGES; e += stride)
        atomicAdd(&hist[dst[e] >> 8], 1);
    __syncthreads();
    for (int i = threadIdx.x; i < NBUCKET; i += 256) {
        int c = hist[i];
        if (c) atomicAdd(&bucketCnt[i], c);
    }
}

__global__ void bucket_scan_kernel(const int* __restrict__ bucketCnt, int* __restrict__ bucketBase,
                                   int* __restrict__ bucketCur, int* __restrict__ row_ptr) {
    __shared__ int s[512];
    int tid = threadIdx.x;
    int v = (tid < NBUCKET) ? bucketCnt[tid] : 0;
    s[tid] = v;
    __syncthreads();
    for (int off = 1; off < 512; off <<= 1) {
        int t = (tid >= off) ? s[tid - off] : 0;
        __syncthreads();
        s[tid] += t;
        __syncthreads();
    }
    if (tid < NBUCKET) {
        int base = s[tid] - v;  // exclusive
        bucketBase[tid] = base;
        bucketCur[tid]  = base;
    }
    if (tid == NBUCKET) {                 // total == N_EDGES
        bucketBase[NBUCKET] = s[tid];
        row_ptr[N_NODES]    = s[tid];
    }
}

// scatter packed (src | (dst&255)<<17) into bucket-partitioned array
__global__ void partition_kernel(const int* __restrict__ src, const int* __restrict__ dst,
                                 int* __restrict__ bucketCur, unsigned* __restrict__ part) {
    __shared__ int cnt[NBUCKET];
    __shared__ int base[NBUCKET];
    for (int i = threadIdx.x; i < NBUCKET; i += 256) cnt[i] = 0;
    __syncthreads();
    int blockStart = blockIdx.x * (256 * EPT);
    unsigned rec[EPT];
    int lr[EPT];
    int bkey[EPT];
#pragma unroll
    for (int i = 0; i < EPT; ++i) {
        int e = blockStart + i * 256 + threadIdx.x;
        if (e < N_EDGES) {
            int d = dst[e];
            int b = d >> 8;
            bkey[i] = b;
            lr[i]   = atomicAdd(&cnt[b], 1);
            rec[i]  = (unsigned)src[e] | ((unsigned)(d & 255) << 17);
        } else {
            lr[i] = -1;
        }
    }
    __syncthreads();
    for (int i = threadIdx.x; i < NBUCKET; i += 256) {
        int c = cnt[i];
        base[i] = c ? atomicAdd(&bucketCur[i], c) : 0;
    }
    __syncthreads();
#pragma unroll
    for (int i = 0; i < EPT; ++i)
        if (lr[i] >= 0) part[base[bkey[i]] + lr[i]] = rec[i];
}

// one block per bucket: local count/scan/fill, all LDS; also emits dinv
__global__ void build_csr_kernel(const unsigned* __restrict__ part, const int* __restrict__ bucketBase,
                                 int* __restrict__ row_ptr, float* __restrict__ dinv,
                                 int* __restrict__ csr) {
    __shared__ int ncnt[256];
    __shared__ int s[256];
    int b   = blockIdx.x;
    int tid = threadIdx.x;
    int beg = bucketBase[b], end = bucketBase[b + 1];
    ncnt[tid] = 0;
    __syncthreads();
    for (int j = beg + tid; j < end; j += 256)
        atomicAdd(&ncnt[part[j] >> 17], 1);
    __syncthreads();
    int deg = ncnt[tid];
    s[tid] = deg;
    __syncthreads();
    for (int off = 1; off < 256; off <<= 1) {
        int t = (tid >= off) ? s[tid - off] : 0;
        __syncthreads();
        s[tid] += t;
        __syncthreads();
    }
    int excl = s[tid] - deg;
    int node = b * 256 + tid;
    if (node < N_NODES) {
        row_ptr[node] = beg + excl;
        dinv[node]    = rsqrtf((float)(deg + 1));  // +1 self-loop
    }
    ncnt[tid] = excl;   // reuse as fill cursor
    __syncthreads();
    for (int j = beg + tid; j < end; j += 256) {
        unsigned r = part[j];
        int v = r >> 17;
        int slot = beg + atomicAdd(&ncnt[v], 1);
        csr[slot] = (int)(r & 0x1FFFFu);
    }
}

// ---------------- layer kernels (g, h stored fp16: row = 16 halves = 32B) ----------------

__device__ __forceinline__ void pack_store_row(__half* dstp, int v, const float* o) {
    int4 w0, w1;
    __half2 q;
    q = __floats2half2_rn(o[0],  o[1]);  w0.x = *(int*)&q;
    q = __floats2half2_rn(o[2],  o[3]);  w0.y = *(int*)&q;
    q = __floats2half2_rn(o[4],  o[5]);  w0.z = *(int*)&q;
    q = __floats2half2_rn(o[6],  o[7]);  w0.w = *(int*)&q;
    q = __floats2half2_rn(o[8],  o[9]);  w1.x = *(int*)&q;
    q = __floats2half2_rn(o[10], o[11]); w1.y = *(int*)&q;
    q = __floats2half2_rn(o[12], o[13]); w1.z = *(int*)&q;
    q = __floats2half2_rn(o[14], o[15]); w1.w = *(int*)&q;
    ((int4*)dstp)[v * 2]     = w0;
    ((int4*)dstp)[v * 2 + 1] = w1;
}

// g[v] = dinv[v] * (x[v] @ W1), x: [N,128] fp32, W: [128,16], g: fp16
__global__ void transform_x_kernel(const float* __restrict__ x, const float* __restrict__ W,
                                   const float* __restrict__ dinv, __half* __restrict__ g) {
    __shared__ float Wl[N_FEAT * HIDDEN];
    int tid = threadIdx.x;
    for (int i = tid; i < N_FEAT * HIDDEN; i += 256) Wl[i] = W[i];
    __syncthreads();
    int v = blockIdx.x * 256 + tid;
    if (v >= N_NODES) return;
    float acc[HIDDEN];
#pragma unroll
    for (int f = 0; f < HIDDEN; ++f) acc[f] = 0.f;
    const float4* xr = (const float4*)(x + (size_t)v * N_FEAT);
#pragma unroll 4
    for (int k4 = 0; k4 < N_FEAT / 4; ++k4) {
        float4 xv = xr[k4];
        const float* wr = &Wl[k4 * 4 * HIDDEN];
#pragma unroll
        for (int f = 0; f < HIDDEN; ++f)
            acc[f] += xv.x * wr[f] + xv.y * wr[HIDDEN + f] +
                      xv.z * wr[2 * HIDDEN + f] + xv.w * wr[3 * HIDDEN + f];
    }
    float di = dinv[v];
#pragma unroll
    for (int f = 0; f < HIDDEN; ++f) acc[f] *= di;
    pack_store_row(g, v, acc);
}

// g[v] = dinv[v] * (h[v] @ W), h: [N,16] fp16, W: [16,16], g: fp16
__global__ void transform_h_kernel(const __half* __restrict__ h, const float* __restrict__ W,
                                   const float* __restrict__ dinv, __half* __restrict__ g) {
    __shared__ float Wl[HIDDEN * HIDDEN];
    int tid = threadIdx.x;
    if (tid < HIDDEN * HIDDEN) Wl[tid] = W[tid];
    __syncthreads();
    int v = blockIdx.x * 256 + tid;
    if (v >= N_NODES) return;
    int4 r0 = ((const int4*)h)[v * 2];
    int4 r1 = ((const int4*)h)[v * 2 + 1];
    float hv[HIDDEN];
    {
        const int rr[8] = {r0.x, r0.y, r0.z, r0.w, r1.x, r1.y, r1.z, r1.w};
#pragma unroll
        for (int q = 0; q < 8; ++q) {
            __half2 p = *(const __half2*)&rr[q];
            float2 f2 = __half22float2(p);
            hv[q * 2] = f2.x; hv[q * 2 + 1] = f2.y;
        }
    }
    float acc[HIDDEN];
#pragma unroll
    for (int f = 0; f < HIDDEN; ++f) acc[f] = 0.f;
#pragma unroll
    for (int k = 0; k < HIDDEN; ++k) {
        float hk = hv[k];
#pragma unroll
        for (int f = 0; f < HIDDEN; ++f) acc[f] += hk * Wl[k * HIDDEN + f];
    }
    float di = dinv[v];
#pragma unroll
    for (int f = 0; f < HIDDEN; ++f) acc[f] *= di;
    pack_store_row(g, v, acc);
}

// h[v][f] = act( dinv[v] * (g[v][f] + sum_{in-edges} g[src][f]) + bias[f] )
// lane layout in wave: lane = c*16 + vl*2 + hh   (c: edge chunk 0..3, vl: node 0..7, hh: feat half)
// each lane gathers 16B (8 halves); chunk partials combined via shfl_xor 16/32
__global__ void aggregate_kernel(const __half* __restrict__ g, const int* __restrict__ row_ptr,
                                 const int* __restrict__ csr, const float* __restrict__ dinv,
                                 const float* __restrict__ bias, __half* __restrict__ hout,
                                 int do_relu) {
    int tid  = threadIdx.x;
    int wave = tid >> 6;
    int l    = tid & 63;
    int c  = l >> 4;
    int vl = (l & 15) >> 1;
    int hh = l & 1;
    int v = blockIdx.x * 32 + wave * 8 + vl;
    if (v >= N_NODES) return;
    int beg = row_ptr[v];
    int deg = row_ptr[v + 1] - beg;
    int j0 = beg + ((deg * c) >> 2);
    int j1 = beg + ((deg * (c + 1)) >> 2);
    const int4* g4 = (const int4*)g;
    float a0 = 0.f, a1 = 0.f, a2 = 0.f, a3 = 0.f, a4 = 0.f, a5 = 0.f, a6 = 0.f, a7 = 0.f;
#pragma unroll 4
    for (int j = j0; j < j1; ++j) {
        int s = csr[j];
        int4 r = g4[s * 2 + hh];
        float2 f0 = __half22float2(*(const __half2*)&r.x);
        float2 f1 = __half22float2(*(const __half2*)&r.y);
        float2 f2 = __half22float2(*(const __half2*)&r.z);
        float2 f3 = __half22float2(*(const __half2*)&r.w);
        a0 += f0.x; a1 += f0.y; a2 += f1.x; a3 += f1.y;
        a4 += f2.x; a5 += f2.y; a6 += f3.x; a7 += f3.y;
    }
    // combine the 4 edge-chunk partials (lanes differing in bits 4,5)
    a0 += __shfl_xor(a0, 16); a1 += __shfl_xor(a1, 16);
    a2 += __shfl_xor(a2, 16); a3 += __shfl_xor(a3, 16);
    a4 += __shfl_xor(a4, 16); a5 += __shfl_xor(a5, 16);
    a6 += __shfl_xor(a6, 16); a7 += __shfl_xor(a7, 16);
    a0 += __shfl_xor(a0, 32); a1 += __shfl_xor(a1, 32);
    a2 += __shfl_xor(a2, 32); a3 += __shfl_xor(a3, 32);
    a4 += __shfl_xor(a4, 32); a5 += __shfl_xor(a5, 32);
    a6 += __shfl_xor(a6, 32); a7 += __shfl_xor(a7, 32);
    if (c == 0) {
        int4 r = g4[v * 2 + hh];  // self-loop contribution
        float2 s0 = __half22float2(*(const __half2*)&r.x);
        float2 s1 = __half22float2(*(const __half2*)&r.y);
        float2 s2 = __half22float2(*(const __half2*)&r.z);
        float2 s3 = __half22float2(*(const __half2*)&r.w);
        float di = dinv[v];
        const float4* bp = (const float4*)bias;
        float4 bA = bp[hh * 2];
        float4 bB = bp[hh * 2 + 1];
        float o0 = di * (a0 + s0.x) + bA.x;
        float o1 = di * (a1 + s0.y) + bA.y;
        float o2 = di * (a2 + s1.x) + bA.z;
        float o3 = di * (a3 + s1.y) + bA.w;
        float o4 = di * (a4 + s2.x) + bB.x;
        float o5 = di * (a5 + s2.y) + bB.y;
        float o6 = di * (a6 + s3.x) + bB.z;
        float o7 = di * (a7 + s3.y) + bB.w;
        if (do_relu) {
            o0 = fmaxf(o0, 0.f); o1 = fmaxf(o1, 0.f); o2 = fmaxf(o2, 0.f); o3 = fmaxf(o3, 0.f);
            o4 = fmaxf(o4, 0.f); o5 = fmaxf(o5, 0.f); o6 = fmaxf(o6, 0.f); o7 = fmaxf(o7, 0.f);
        }
        int4 w;
        __half2 q;
        q = __floats2half2_rn(o0, o1); w.x = *(int*)&q;
        q = __floats2half2_rn(o2, o3); w.y = *(int*)&q;
        q = __floats2half2_rn(o4, o5); w.z = *(int*)&q;
        q = __floats2half2_rn(o6, o7); w.w = *(int*)&q;
        ((int4*)hout)[v * 2 + hh] = w;
    }
}

// ---------------- pooling + head ----------------

__global__ void pool_kernel(const __half* __restrict__ h, const int* __restrict__ batch,
                            float* __restrict__ pooled) {
    int idx = blockIdx.x * 256 + threadIdx.x;
    if (idx < N_NODES * HIDDEN) {
        int v = idx >> 4;
        int f = idx & 15;
        atomicAdd(&pooled[batch[v] * HIDDEN + f], __half2float(h[idx]));
    }
}

__global__ void head_kernel(const float* __restrict__ pooled, const float* __restrict__ Wlin,
                            const float* __restrict__ blin, float* __restrict__ out) {
    int idx = blockIdx.x * 256 + threadIdx.x;
    if (idx < N_GRAPHS * N_CLASSES) {
        int gi = idx / N_CLASSES;
        int c  = idx % N_CLASSES;
        float s = blin[c];
#pragma unroll
        for (int f = 0; f < HIDDEN; ++f) s += pooled[gi * HIDDEN + f] * Wlin[f * N_CLASSES + c];
        out[idx] = s;
    }
}

// ---------------- launch ----------------

extern "C" void kernel_launch(void* const* d_in, const int* in_sizes, int n_in,
                              void* d_out, int out_size, void* d_ws, size_t ws_size,
                              hipStream_t stream) {
    const float* x     = (const float*)d_in[0];
    const int*   ei    = (const int*)d_in[1];
    const int*   src   = ei;
    const int*   dst   = ei + N_EDGES;
    const int*   batch = (const int*)d_in[2];
    const float* W1 = (const float*)d_in[3];
    const float* b1 = (const float*)d_in[4];
    const float* W2 = (const float*)d_in[5];
    const float* b2 = (const float*)d_in[6];
    const float* W3 = (const float*)d_in[7];
    const float* b3 = (const float*)d_in[8];
    const float* Wlin = (const float*)d_in[9];
    const float* blin = (const float*)d_in[10];
    float* out = (float*)d_out;

    char* w = (char*)d_ws;
    auto alloc = [&](size_t bytes) -> char* {
        char* p = w;
        w += (bytes + 255) & ~(size_t)255;
        return p;
    };
    int*   bucketCnt  = (int*)alloc((size_t)NBUCKET * 4);
    int*   bucketBase = (int*)alloc(((size_t)NBUCKET + 1) * 4);
    int*   bucketCur  = (int*)alloc((size_t)NBUCKET * 4);
    int*   row_ptr    = (int*)alloc(((size_t)N_NODES + 1) * 4);
    float* dinv       = (float*)alloc((size_t)N_NODES * 4);
    float* pooled     = (float*)alloc((size_t)N_GRAPHS * HIDDEN * 4);
    int*   csr        = (int*)alloc((size_t)N_EDGES * 4);
    __half* g         = (__half*)alloc((size_t)N_NODES * HIDDEN * 2);
    // part (12.8 MB) aliases hA+hB (3.2 MB each): part is dead before hA is written
    char*  bigbuf     = alloc((size_t)N_EDGES * 4);
    unsigned* part    = (unsigned*)bigbuf;
    __half* hA        = (__half*)bigbuf;
    __half* hB        = hA + (size_t)N_NODES * HIDDEN;

    hipMemsetAsync(bucketCnt, 0, (size_t)NBUCKET * 4, stream);
    hipMemsetAsync(pooled, 0, (size_t)N_GRAPHS * HIDDEN * 4, stream);

    int nbn = (N_NODES + 255) / 256;
    int ab  = (N_NODES + 31) / 32;
    int pb  = (N_EDGES + 256 * EPT - 1) / (256 * EPT);

    bucket_count_kernel<<<512, 256, 0, stream>>>(dst, bucketCnt);
    bucket_scan_kernel<<<1, 512, 0, stream>>>(bucketCnt, bucketBase, bucketCur, row_ptr);
    partition_kernel<<<pb, 256, 0, stream>>>(src, dst, bucketCur, part);
    build_csr_kernel<<<NBUCKET, 256, 0, stream>>>(part, bucketBase, row_ptr, dinv, csr);

    // layer 1
    transform_x_kernel<<<nbn, 256, 0, stream>>>(x, W1, dinv, g);
    aggregate_kernel<<<ab, 256, 0, stream>>>(g, row_ptr, csr, dinv, b1, hA, 1);
    // layer 2
    transform_h_kernel<<<nbn, 256, 0, stream>>>(hA, W2, dinv, g);
    aggregate_kernel<<<ab, 256, 0, stream>>>(g, row_ptr, csr, dinv, b2, hB, 1);
    // layer 3 (no relu)
    transform_h_kernel<<<nbn, 256, 0, stream>>>(hB, W3, dinv, g);
    aggregate_kernel<<<ab, 256, 0, stream>>>(g, row_ptr, csr, dinv, b3, hA, 0);

    pool_kernel<<<(N_NODES * HIDDEN + 255) / 256, 256, 0, stream>>>(hA, batch, pooled);
    head_kernel<<<(N_GRAPHS * N_CLASSES + 255) / 256, 256, 0, stream>>>(pooled, Wlin, blin, out);
}

// Round 4
// 303.689 us; speedup vs baseline: 2.8006x; 1.1503x over previous
//
#include <hip/hip_runtime.h>
#include <hip/hip_fp16.h>

#define N_NODES   100000
#define N_EDGES   3200000
#define N_FEAT    128
#define HIDDEN    16
#define N_CLASSES 10
#define N_GRAPHS  512
#define NBUCKET   391      // ceil(N_NODES / 256)
#define EPT       16       // edges per thread in partition (4096/block)

// ---------------- CSR build (two-level counting sort by dst) ----------------

__global__ void bucket_count_kernel(const int* __restrict__ dst, int* __restrict__ bucketCnt) {
    __shared__ int hist[NBUCKET];
    for (int i = threadIdx.x; i < NBUCKET; i += 256) hist[i] = 0;
    __syncthreads();
    int stride = gridDim.x * 256;
    for (int e = blockIdx.x * 256 + threadIdx.x; e < N_EDGES; e += stride)
        atomicAdd(&hist[dst[e] >> 8], 1);
    __syncthreads();
    for (int i = threadIdx.x; i < NBUCKET; i += 256) {
        int c = hist[i];
        if (c) atomicAdd(&bucketCnt[i], c);
    }
}

__global__ void bucket_scan_kernel(const int* __restrict__ bucketCnt, int* __restrict__ bucketBase,
                                   int* __restrict__ bucketCur, int* __restrict__ row_ptr) {
    __shared__ int s[512];
    int tid = threadIdx.x;
    int v = (tid < NBUCKET) ? bucketCnt[tid] : 0;
    s[tid] = v;
    __syncthreads();
    for (int off = 1; off < 512; off <<= 1) {
        int t = (tid >= off) ? s[tid - off] : 0;
        __syncthreads();
        s[tid] += t;
        __syncthreads();
    }
    if (tid < NBUCKET) {
        int base = s[tid] - v;  // exclusive
        bucketBase[tid] = base;
        bucketCur[tid]  = base;
    }
    if (tid == NBUCKET) {                 // total == N_EDGES
        bucketBase[NBUCKET] = s[tid];
        row_ptr[N_NODES]    = s[tid];
    }
}

// scatter packed (src | (dst&255)<<17) into bucket-partitioned array
__global__ void partition_kernel(const int* __restrict__ src, const int* __restrict__ dst,
                                 int* __restrict__ bucketCur, unsigned* __restrict__ part) {
    __shared__ int cnt[NBUCKET];
    __shared__ int base[NBUCKET];
    for (int i = threadIdx.x; i < NBUCKET; i += 256) cnt[i] = 0;
    __syncthreads();
    int blockStart = blockIdx.x * (256 * EPT);
    unsigned rec[EPT];
    int lr[EPT];
    int bkey[EPT];
#pragma unroll
    for (int i = 0; i < EPT; ++i) {
        int e = blockStart + i * 256 + threadIdx.x;
        if (e < N_EDGES) {
            int d = dst[e];
            int b = d >> 8;
            bkey[i] = b;
            lr[i]   = atomicAdd(&cnt[b], 1);
            rec[i]  = (unsigned)src[e] | ((unsigned)(d & 255) << 17);
        } else {
            lr[i] = -1;
        }
    }
    __syncthreads();
    for (int i = threadIdx.x; i < NBUCKET; i += 256) {
        int c = cnt[i];
        base[i] = c ? atomicAdd(&bucketCur[i], c) : 0;
    }
    __syncthreads();
#pragma unroll
    for (int i = 0; i < EPT; ++i)
        if (lr[i] >= 0) part[base[bkey[i]] + lr[i]] = rec[i];
}

// one block per bucket: local count/scan/fill, all LDS; also emits dinv
__global__ void build_csr_kernel(const unsigned* __restrict__ part, const int* __restrict__ bucketBase,
                                 int* __restrict__ row_ptr, float* __restrict__ dinv,
                                 int* __restrict__ csr) {
    __shared__ int ncnt[256];
    __shared__ int s[256];
    int b   = blockIdx.x;
    int tid = threadIdx.x;
    int beg = bucketBase[b], end = bucketBase[b + 1];
    ncnt[tid] = 0;
    __syncthreads();
    for (int j = beg + tid; j < end; j += 256)
        atomicAdd(&ncnt[part[j] >> 17], 1);
    __syncthreads();
    int deg = ncnt[tid];
    s[tid] = deg;
    __syncthreads();
    for (int off = 1; off < 256; off <<= 1) {
        int t = (tid >= off) ? s[tid - off] : 0;
        __syncthreads();
        s[tid] += t;
        __syncthreads();
    }
    int excl = s[tid] - deg;
    int node = b * 256 + tid;
    if (node < N_NODES) {
        row_ptr[node] = beg + excl;
        dinv[node]    = rsqrtf((float)(deg + 1));  // +1 self-loop
    }
    ncnt[tid] = excl;   // reuse as fill cursor
    __syncthreads();
    for (int j = beg + tid; j < end; j += 256) {
        unsigned r = part[j];
        int v = r >> 17;
        int slot = beg + atomicAdd(&ncnt[v], 1);
        csr[slot] = (int)(r & 0x1FFFFu);
    }
}

// ---------------- layer kernels (g, h stored fp16: row = 16 halves = 32B) ----------------

__device__ __forceinline__ void pack_store_row(__half* dstp, int v, const float* o) {
    int4 w0, w1;
    __half2 q;
    q = __floats2half2_rn(o[0],  o[1]);  w0.x = *(int*)&q;
    q = __floats2half2_rn(o[2],  o[3]);  w0.y = *(int*)&q;
    q = __floats2half2_rn(o[4],  o[5]);  w0.z = *(int*)&q;
    q = __floats2half2_rn(o[6],  o[7]);  w0.w = *(int*)&q;
    q = __floats2half2_rn(o[8],  o[9]);  w1.x = *(int*)&q;
    q = __floats2half2_rn(o[10], o[11]); w1.y = *(int*)&q;
    q = __floats2half2_rn(o[12], o[13]); w1.z = *(int*)&q;
    q = __floats2half2_rn(o[14], o[15]); w1.w = *(int*)&q;
    ((int4*)dstp)[v * 2]     = w0;
    ((int4*)dstp)[v * 2 + 1] = w1;
}

// g[v] = dinv[v] * (x[v] @ W1), x: [N,128] fp32, W: [128,16], g: fp16
__global__ void transform_x_kernel(const float* __restrict__ x, const float* __restrict__ W,
                                   const float* __restrict__ dinv, __half* __restrict__ g) {
    __shared__ float Wl[N_FEAT * HIDDEN];
    int tid = threadIdx.x;
    for (int i = tid; i < N_FEAT * HIDDEN; i += 256) Wl[i] = W[i];
    __syncthreads();
    int v = blockIdx.x * 256 + tid;
    if (v >= N_NODES) return;
    float acc[HIDDEN];
#pragma unroll
    for (int f = 0; f < HIDDEN; ++f) acc[f] = 0.f;
    const float4* xr = (const float4*)(x + (size_t)v * N_FEAT);
#pragma unroll 4
    for (int k4 = 0; k4 < N_FEAT / 4; ++k4) {
        float4 xv = xr[k4];
        const float* wr = &Wl[k4 * 4 * HIDDEN];
#pragma unroll
        for (int f = 0; f < HIDDEN; ++f)
            acc[f] += xv.x * wr[f] + xv.y * wr[HIDDEN + f] +
                      xv.z * wr[2 * HIDDEN + f] + xv.w * wr[3 * HIDDEN + f];
    }
    float di = dinv[v];
#pragma unroll
    for (int f = 0; f < HIDDEN; ++f) acc[f] *= di;
    pack_store_row(g, v, acc);
}

// g[v] = dinv[v] * (h[v] @ W), h: [N,16] fp16, W: [16,16], g: fp16
__global__ void transform_h_kernel(const __half* __restrict__ h, const float* __restrict__ W,
                                   const float* __restrict__ dinv, __half* __restrict__ g) {
    __shared__ float Wl[HIDDEN * HIDDEN];
    int tid = threadIdx.x;
    if (tid < HIDDEN * HIDDEN) Wl[tid] = W[tid];
    __syncthreads();
    int v = blockIdx.x * 256 + tid;
    if (v >= N_NODES) return;
    int4 r0 = ((const int4*)h)[v * 2];
    int4 r1 = ((const int4*)h)[v * 2 + 1];
    float hv[HIDDEN];
    {
        const int rr[8] = {r0.x, r0.y, r0.z, r0.w, r1.x, r1.y, r1.z, r1.w};
#pragma unroll
        for (int q = 0; q < 8; ++q) {
            __half2 p = *(const __half2*)&rr[q];
            float2 f2 = __half22float2(p);
            hv[q * 2] = f2.x; hv[q * 2 + 1] = f2.y;
        }
    }
    float acc[HIDDEN];
#pragma unroll
    for (int f = 0; f < HIDDEN; ++f) acc[f] = 0.f;
#pragma unroll
    for (int k = 0; k < HIDDEN; ++k) {
        float hk = hv[k];
#pragma unroll
        for (int f = 0; f < HIDDEN; ++f) acc[f] += hk * Wl[k * HIDDEN + f];
    }
    float di = dinv[v];
#pragma unroll
    for (int f = 0; f < HIDDEN; ++f) acc[f] *= di;
    pack_store_row(g, v, acc);
}

// h[v][f] = act( dinv[v] * (g[v][f] + sum_{in-edges} g[src][f]) + bias[f] )
// lane layout in wave: lane = c*16 + vl*2 + hh   (c: edge chunk 0..3, vl: node 0..7, hh: feat half)
__global__ void aggregate_kernel(const __half* __restrict__ g, const int* __restrict__ row_ptr,
                                 const int* __restrict__ csr, const float* __restrict__ dinv,
                                 const float* __restrict__ bias, __half* __restrict__ hout,
                                 int do_relu) {
    int tid  = threadIdx.x;
    int wave = tid >> 6;
    int l    = tid & 63;
    int c  = l >> 4;
    int vl = (l & 15) >> 1;
    int hh = l & 1;
    int v = blockIdx.x * 32 + wave * 8 + vl;
    if (v >= N_NODES) return;
    int beg = row_ptr[v];
    int deg = row_ptr[v + 1] - beg;
    int j0 = beg + ((deg * c) >> 2);
    int j1 = beg + ((deg * (c + 1)) >> 2);
    const int4* g4 = (const int4*)g;
    float a0 = 0.f, a1 = 0.f, a2 = 0.f, a3 = 0.f, a4 = 0.f, a5 = 0.f, a6 = 0.f, a7 = 0.f;
#pragma unroll 4
    for (int j = j0; j < j1; ++j) {
        int s = csr[j];
        int4 r = g4[s * 2 + hh];
        float2 f0 = __half22float2(*(const __half2*)&r.x);
        float2 f1 = __half22float2(*(const __half2*)&r.y);
        float2 f2 = __half22float2(*(const __half2*)&r.z);
        float2 f3 = __half22float2(*(const __half2*)&r.w);
        a0 += f0.x; a1 += f0.y; a2 += f1.x; a3 += f1.y;
        a4 += f2.x; a5 += f2.y; a6 += f3.x; a7 += f3.y;
    }
    a0 += __shfl_xor(a0, 16); a1 += __shfl_xor(a1, 16);
    a2 += __shfl_xor(a2, 16); a3 += __shfl_xor(a3, 16);
    a4 += __shfl_xor(a4, 16); a5 += __shfl_xor(a5, 16);
    a6 += __shfl_xor(a6, 16); a7 += __shfl_xor(a7, 16);
    a0 += __shfl_xor(a0, 32); a1 += __shfl_xor(a1, 32);
    a2 += __shfl_xor(a2, 32); a3 += __shfl_xor(a3, 32);
    a4 += __shfl_xor(a4, 32); a5 += __shfl_xor(a5, 32);
    a6 += __shfl_xor(a6, 32); a7 += __shfl_xor(a7, 32);
    if (c == 0) {
        int4 r = g4[v * 2 + hh];  // self-loop contribution
        float2 s0 = __half22float2(*(const __half2*)&r.x);
        float2 s1 = __half22float2(*(const __half2*)&r.y);
        float2 s2 = __half22float2(*(const __half2*)&r.z);
        float2 s3 = __half22float2(*(const __half2*)&r.w);
        float di = dinv[v];
        const float4* bp = (const float4*)bias;
        float4 bA = bp[hh * 2];
        float4 bB = bp[hh * 2 + 1];
        float o0 = di * (a0 + s0.x) + bA.x;
        float o1 = di * (a1 + s0.y) + bA.y;
        float o2 = di * (a2 + s1.x) + bA.z;
        float o3 = di * (a3 + s1.y) + bA.w;
        float o4 = di * (a4 + s2.x) + bB.x;
        float o5 = di * (a5 + s2.y) + bB.y;
        float o6 = di * (a6 + s3.x) + bB.z;
        float o7 = di * (a7 + s3.y) + bB.w;
        if (do_relu) {
            o0 = fmaxf(o0, 0.f); o1 = fmaxf(o1, 0.f); o2 = fmaxf(o2, 0.f); o3 = fmaxf(o3, 0.f);
            o4 = fmaxf(o4, 0.f); o5 = fmaxf(o5, 0.f); o6 = fmaxf(o6, 0.f); o7 = fmaxf(o7, 0.f);
        }
        int4 w;
        __half2 q;
        q = __floats2half2_rn(o0, o1); w.x = *(int*)&q;
        q = __floats2half2_rn(o2, o3); w.y = *(int*)&q;
        q = __floats2half2_rn(o4, o5); w.z = *(int*)&q;
        q = __floats2half2_rn(o6, o7); w.w = *(int*)&q;
        ((int4*)hout)[v * 2 + hh] = w;
    }
}

// ---------------- fused pooling + head (batch is sorted -> contiguous graph ranges) ----------------

__global__ void pool_head_kernel(const __half* __restrict__ h, const int* __restrict__ batch,
                                 const float* __restrict__ Wlin, const float* __restrict__ blin,
                                 float* __restrict__ out) {
    __shared__ float red[256];
    __shared__ int bounds[2];
    int g   = blockIdx.x;
    int tid = threadIdx.x;
    if (tid < 2) {
        int target = g + tid;   // lower_bound(batch, target)
        int lo = 0, hi = N_NODES;
        while (lo < hi) {
            int mid = (lo + hi) >> 1;
            if (batch[mid] < target) lo = mid + 1; else hi = mid;
        }
        bounds[tid] = lo;
    }
    __syncthreads();
    int start = bounds[0], end = bounds[1];
    int f = tid & 15, r = tid >> 4;
    float acc = 0.f;
    for (int v = start + r; v < end; v += 16)
        acc += __half2float(h[v * HIDDEN + f]);
    red[tid] = acc;
    __syncthreads();
    for (int off = 128; off >= 16; off >>= 1) {
        if (tid < off) red[tid] += red[tid + off];
        __syncthreads();
    }
    if (tid < N_CLASSES) {
        float s = blin[tid];
#pragma unroll
        for (int fe = 0; fe < HIDDEN; ++fe) s += red[fe] * Wlin[fe * N_CLASSES + tid];
        out[g * N_CLASSES + tid] = s;
    }
}

// ---------------- launch ----------------

extern "C" void kernel_launch(void* const* d_in, const int* in_sizes, int n_in,
                              void* d_out, int out_size, void* d_ws, size_t ws_size,
                              hipStream_t stream) {
    const float* x     = (const float*)d_in[0];
    const int*   ei    = (const int*)d_in[1];
    const int*   src   = ei;
    const int*   dst   = ei + N_EDGES;
    const int*   batch = (const int*)d_in[2];
    const float* W1 = (const float*)d_in[3];
    const float* b1 = (const float*)d_in[4];
    const float* W2 = (const float*)d_in[5];
    const float* b2 = (const float*)d_in[6];
    const float* W3 = (const float*)d_in[7];
    const float* b3 = (const float*)d_in[8];
    const float* Wlin = (const float*)d_in[9];
    const float* blin = (const float*)d_in[10];
    float* out = (float*)d_out;

    char* w = (char*)d_ws;
    auto alloc = [&](size_t bytes) -> char* {
        char* p = w;
        w += (bytes + 255) & ~(size_t)255;
        return p;
    };
    int*   bucketCnt  = (int*)alloc((size_t)NBUCKET * 4);
    int*   bucketBase = (int*)alloc(((size_t)NBUCKET + 1) * 4);
    int*   bucketCur  = (int*)alloc((size_t)NBUCKET * 4);
    int*   row_ptr    = (int*)alloc(((size_t)N_NODES + 1) * 4);
    float* dinv       = (float*)alloc((size_t)N_NODES * 4);
    int*   csr        = (int*)alloc((size_t)N_EDGES * 4);
    __half* g         = (__half*)alloc((size_t)N_NODES * HIDDEN * 2);
    // part (12.8 MB) aliases hA+hB (3.2 MB each): part is dead before hA is written
    char*  bigbuf     = alloc((size_t)N_EDGES * 4);
    unsigned* part    = (unsigned*)bigbuf;
    __half* hA        = (__half*)bigbuf;
    __half* hB        = hA + (size_t)N_NODES * HIDDEN;

    hipMemsetAsync(bucketCnt, 0, (size_t)NBUCKET * 4, stream);

    int nbn = (N_NODES + 255) / 256;
    int ab  = (N_NODES + 31) / 32;
    int pb  = (N_EDGES + 256 * EPT - 1) / (256 * EPT);

    bucket_count_kernel<<<512, 256, 0, stream>>>(dst, bucketCnt);
    bucket_scan_kernel<<<1, 512, 0, stream>>>(bucketCnt, bucketBase, bucketCur, row_ptr);
    partition_kernel<<<pb, 256, 0, stream>>>(src, dst, bucketCur, part);
    build_csr_kernel<<<NBUCKET, 256, 0, stream>>>(part, bucketBase, row_ptr, dinv, csr);

    // layer 1
    transform_x_kernel<<<nbn, 256, 0, stream>>>(x, W1, dinv, g);
    aggregate_kernel<<<ab, 256, 0, stream>>>(g, row_ptr, csr, dinv, b1, hA, 1);
    // layer 2
    transform_h_kernel<<<nbn, 256, 0, stream>>>(hA, W2, dinv, g);
    aggregate_kernel<<<ab, 256, 0, stream>>>(g, row_ptr, csr, dinv, b2, hB, 1);
    // layer 3 (no relu)
    transform_h_kernel<<<nbn, 256, 0, stream>>>(hB, W3, dinv, g);
    aggregate_kernel<<<ab, 256, 0, stream>>>(g, row_ptr, csr, dinv, b3, hA, 0);

    pool_head_kernel<<<N_GRAPHS, 256, 0, stream>>>(hA, batch, Wlin, blin, out);
}